// Round 6
// baseline (12200.069 us; speedup 1.0000x reference)
//
#include <hip/hip_runtime.h>

// ---------------------------------------------------------------------------
// 2-layer ReLU RNN, B=64 T=2048 IN=256 H=512 C=128. fp32 inputs (runtime
// dtype detect kept), output dtype matches input.
//
// Round-6: ONE persistent fused kernel runs both layers pipelined (L1 lags L0
// by 1 step). Input projections folded into the scan (x_t@Wih0 inside L0,
// h0_t@Wih1 inside L1) -> no GEMM dispatches, no pre/h buffers (ws ~2.6MB).
//
// Grid = 32 WGs x 256 thr (1 wave/SIMD, 512-VGPR budget): L = bid>>4,
// r = (bid>>2)&3 (16 batch rows), cg = bid&3 (128 h cols). Weights in VGPRs:
// L0 wave 192 (Wih0 64 + Whh0 128), L1 wave 256 (Wih1 128 + Whh1 128).
// Exchange: r5's proven self-validating u64 protocol (4 f16, h>=0, 2-bit
// step tag in sign bits; relaxed agent-scope RMWs at the coherence point;
// NO fences), widened to 4 buffers (np = t&3, tag=(t>>1)&3; overwrite
// distance 4, tag-alias distance 8 unreachable given lead bounds).
// Back-pressure: L1 publishes progress[r][cg]=t+1 after consuming h0_t;
// L0 publishes h0_t only when min progress >= t-3 (poison 0xAA = negative
// -> treated as not-ready; load issued at step top -> latency hidden).
// x_{t+1} prefetched from HBM during step t (off critical path).
// All spins bounded (wrong answer, never hang).
// ---------------------------------------------------------------------------

typedef unsigned short u16;
typedef unsigned int u32;
typedef unsigned long long u64;
typedef _Float16 f16;
typedef _Float16 half8 __attribute__((ext_vector_type(8)));
typedef float float4v __attribute__((ext_vector_type(4)));

#define T_LEN 2048
#define H_DIM 512
#define B_SZ 64
#define SGN 0x8000800080008000ull
#define VMASK 0x7fff7fff7fff7fffull
#define SPIN_LIM (1 << 13)

__device__ __forceinline__ float bf2f(u16 u) {
    union { u32 i; float f; } v; v.i = ((u32)u) << 16; return v.f;
}
__device__ __forceinline__ u16 f2bf(float f) {
    u32 x = __float_as_uint(f);
    u32 r = (x + 0x7fffu + ((x >> 16) & 1u)) >> 16;
    return (u16)r;
}
__device__ __forceinline__ float loadf(const void* p, size_t i, int dt) {
    return dt ? ((const float*)p)[i] : bf2f(((const u16*)p)[i]);
}
__device__ __forceinline__ half8 cvt8_bf16(uint4 v) {
    half8 h;
    h[0] = (f16)bf2f((u16)(v.x & 0xffff)); h[1] = (f16)bf2f((u16)(v.x >> 16));
    h[2] = (f16)bf2f((u16)(v.y & 0xffff)); h[3] = (f16)bf2f((u16)(v.y >> 16));
    h[4] = (f16)bf2f((u16)(v.z & 0xffff)); h[5] = (f16)bf2f((u16)(v.z >> 16));
    h[6] = (f16)bf2f((u16)(v.w & 0xffff)); h[7] = (f16)bf2f((u16)(v.w >> 16));
    return h;
}
// 2-bit tag for step t, encoded in the 4 f16 sign bits of a u64.
__device__ __forceinline__ u64 tagmask(int t) {
    int tg = (t >> 1) & 3;
    return ((tg & 1) ? 0x0000800000008000ull : 0ull) |
           ((tg & 2) ? 0x8000000080000000ull : 0ull);
}

// --------------------------- dtype detection -------------------------------
__global__ void detect_kernel(const u16* __restrict__ xr, int* __restrict__ dtf) {
    int lane = threadIdx.x;
    u16 u0 = xr[(lane * 2 + 0) * 2];
    u16 u1 = xr[(lane * 2 + 1) * 2];
    int e0 = (u0 >> 7) & 0xff, e1 = (u1 >> 7) & 0xff;
    int c0 = (e0 >= 0x60 && e0 <= 0x8f) ? 1 : 0;
    int c1 = (e1 >= 0x60 && e1 <= 0x8f) ? 1 : 0;
    int tot = __popcll(__ballot(c0)) + __popcll(__ballot(c1));
    if (lane == 0) *dtf = (tot >= 96) ? 0 : 1;   // 0 = bf16, 1 = fp32
}

// --------------------------- prep kernels ----------------------------------
__global__ void cvt_w_kernel(const void* __restrict__ in, f16* __restrict__ out,
                             int n, const int* __restrict__ dtf) {
    int dt = *dtf;
    for (int i = blockIdx.x * blockDim.x + threadIdx.x; i < n; i += gridDim.x * blockDim.x)
        out[i] = (f16)loadf(in, i, dt);
}

__global__ void bias_kernel(const void* __restrict__ bi, const void* __restrict__ bh,
                            float* __restrict__ bias, const int* __restrict__ dtf) {
    int dt = *dtf;
    int i = blockIdx.x * blockDim.x + threadIdx.x;
    if (i < H_DIM) bias[i] = loadf(bi, i, dt) + loadf(bh, i, dt);
}

__global__ void fcb_kernel(const void* __restrict__ in, float* __restrict__ out,
                           const int* __restrict__ dtf) {
    int i = threadIdx.x;
    if (i < 128) out[i] = loadf(in, i, *dtf);
}

// --------------------------- fused 2-layer scan ----------------------------
__global__ __launch_bounds__(256, 1)
void fused_rnn_kernel(const void* __restrict__ xr,     // [B,T,256] raw dtype
                      const f16* __restrict__ Wih0,    // [512,256]
                      const f16* __restrict__ Whh0,    // [512,512]
                      const f16* __restrict__ Wih1,    // [512,512]
                      const f16* __restrict__ Whh1,    // [512,512]
                      const float* __restrict__ bias0, const float* __restrict__ bias1,
                      u64* __restrict__ hex0,          // [4][64][128] u64
                      u64* __restrict__ hex1,          // [4][64][128] u64
                      int* __restrict__ prog,          // [16] L1 progress
                      float* __restrict__ hlast,       // [64,512] fp32
                      const int* __restrict__ dtf)
{
    __shared__ f16 stage[4][16 * 512];   // [0..1]: h(layer) dbuf; [2..3]: h0 stage (L1)
    const int bid = blockIdx.x;
    const int L = bid >> 4, sub = bid & 15, r = sub >> 2, cg = sub & 3;
    const int rows0 = r * 16;
    const int tid = threadIdx.x;
    const int w = tid >> 6, lane = tid & 63;
    const int lr = lane & 15, quad = lane >> 4;
    const int c0w = cg * 128 + w * 32;
    const int dt = *dtf;

    // remote/publish thread mapping
    const int rrow = tid >> 4;             // row within 16-row group
    const int rc8 = (tid & 15) * 8;        // first of 8 u64 cols
    const bool mine = ((tid & 15) >> 2) == cg;
    const int prow = tid >> 4, poc = (tid & 15) * 2;

    if (L == 0) {
        // ---------------- layer 0 ----------------
        half8 Bih[2][8], Bhh[2][16];
#pragma unroll
        for (int j = 0; j < 2; ++j) {
#pragma unroll
            for (int kc = 0; kc < 8; ++kc)
                Bih[j][kc] = *(const half8*)(Wih0 + (size_t)(c0w + j * 16 + lr) * 256
                                             + kc * 32 + quad * 8);
#pragma unroll
            for (int kc = 0; kc < 16; ++kc)
                Bhh[j][kc] = *(const half8*)(Whh0 + (size_t)(c0w + j * 16 + lr) * H_DIM
                                             + kc * 32 + quad * 8);
        }
        const float b0[2] = {bias0[c0w + lr], bias0[c0w + 16 + lr]};

        // x prefetch registers (one step ahead)
        float4v xr32[16];
        uint4 xr16[8];
        auto loadx = [&](int t) {
            if (dt) {
                const float* xp = (const float*)xr
                    + ((size_t)(rows0 + lr) * T_LEN + t) * 256 + quad * 8;
#pragma unroll
                for (int kc = 0; kc < 8; ++kc) {
                    xr32[2 * kc]     = *(const float4v*)(xp + kc * 32);
                    xr32[2 * kc + 1] = *(const float4v*)(xp + kc * 32 + 4);
                }
            } else {
                const u16* xp = (const u16*)xr
                    + ((size_t)(rows0 + lr) * T_LEN + t) * 256 + quad * 8;
#pragma unroll
                for (int kc = 0; kc < 8; ++kc)
                    xr16[kc] = *(const uint4*)(xp + kc * 32);
            }
        };
        loadx(0);

        for (int t = 0; t < T_LEN; ++t) {
            // back-pressure flag load (evaluated after MFMA; hidden latency)
            int pg = 0x7fffffff;
            if (t >= 4)
                pg = __hip_atomic_load(&prog[r * 4 + (tid & 3)], __ATOMIC_RELAXED,
                                       __HIP_MEMORY_SCOPE_AGENT);

            // x A-frags for this step
            half8 axf[8];
            if (dt) {
#pragma unroll
                for (int kc = 0; kc < 8; ++kc) {
                    float4v f0 = xr32[2 * kc], f1 = xr32[2 * kc + 1];
                    half8 h;
                    h[0]=(f16)f0[0]; h[1]=(f16)f0[1]; h[2]=(f16)f0[2]; h[3]=(f16)f0[3];
                    h[4]=(f16)f1[0]; h[5]=(f16)f1[1]; h[6]=(f16)f1[2]; h[7]=(f16)f1[3];
                    axf[kc] = h;
                }
            } else {
#pragma unroll
                for (int kc = 0; kc < 8; ++kc) axf[kc] = cvt8_bf16(xr16[kc]);
            }

            float4v acc0 = {0.f,0.f,0.f,0.f}, acc1 = {0.f,0.f,0.f,0.f};
#pragma unroll
            for (int kc = 0; kc < 8; ++kc) {
                acc0 = __builtin_amdgcn_mfma_f32_16x16x32_f16(axf[kc], Bih[0][kc], acc0, 0, 0, 0);
                acc1 = __builtin_amdgcn_mfma_f32_16x16x32_f16(axf[kc], Bih[1][kc], acc1, 0, 0, 0);
            }
            if (t > 0) {
                const f16* sb = stage[(t - 1) & 1];
#pragma unroll
                for (int kc = 0; kc < 16; ++kc) {
                    half8 a = *(const half8*)&sb[lr * 512 + (((kc * 4 + quad) ^ (lr & 7)) * 8)];
                    acc0 = __builtin_amdgcn_mfma_f32_16x16x32_f16(a, Bhh[0][kc], acc0, 0, 0, 0);
                    acc1 = __builtin_amdgcn_mfma_f32_16x16x32_f16(a, Bhh[1][kc], acc1, 0, 0, 0);
                }
            }
            if (t + 1 < T_LEN) loadx(t + 1);   // prefetch next x

            // h0_t = relu(acc + b0); stage own slice
            f16* sw = stage[t & 1];
#pragma unroll
            for (int j = 0; j < 2; ++j) {
                const float4v& a = j ? acc1 : acc0;
#pragma unroll
                for (int i = 0; i < 4; ++i) {
                    f16 hv = (f16)fmaxf(a[i] + b0[j], 0.f);
                    int row = quad * 4 + i, lc = c0w + j * 16 + lr;
                    sw[row * 512 + ((lc >> 3) ^ (row & 7)) * 8 + (lc & 7)] = hv;
                }
            }
            __syncthreads();   // own stage visible to publisher threads

            // back-pressure: don't overwrite hex0[t&3] until L1 consumed t-4
            if (t >= 4) {
                const int need = t - 3;
                int g = 0;
                while (!__all(pg >= need) && g < SPIN_LIM) {
                    pg = __hip_atomic_load(&prog[r * 4 + (tid & 3)], __ATOMIC_RELAXED,
                                           __HIP_MEMORY_SCOPE_AGENT);
                    ++g;
                }
            }

            // publish own 2 u64 (tagged)
            const u64 em = tagmask(t);
            {
                int cu = cg * 32 + poc;
                uint4 q4 = *(const uint4*)&stage[t & 1][prow * 512 + (((cu >> 1) ^ (prow & 7)) * 8)];
                u64 v0 = (((u64)q4.y) << 32) | q4.x;
                u64 v1 = (((u64)q4.w) << 32) | q4.z;
                u64* dst = hex0 + ((size_t)(t & 3) * 64 + rows0 + prow) * 128;
                (void)__hip_atomic_exchange(&dst[cu], v0 | em, __ATOMIC_RELAXED,
                                            __HIP_MEMORY_SCOPE_AGENT);
                (void)__hip_atomic_exchange(&dst[cu + 1], v1 | em, __ATOMIC_RELAXED,
                                            __HIP_MEMORY_SCOPE_AGENT);
            }

            // spin sibling slices for next step's A
            if (!mine) {
                u64* src = hex0 + ((size_t)(t & 3) * 64 + rows0 + rrow) * 128 + rc8;
                u64 vv[8];
                int pend = 0xff, g = 0;
                while (pend && g < SPIN_LIM) {
#pragma unroll
                    for (int q = 0; q < 8; ++q)
                        if (pend & (1 << q))
                            vv[q] = __hip_atomic_fetch_or(src + q, 0ull, __ATOMIC_RELAXED,
                                                          __HIP_MEMORY_SCOPE_AGENT);
#pragma unroll
                    for (int q = 0; q < 8; ++q)
                        if ((pend & (1 << q)) && ((vv[q] & SGN) == em)) pend &= ~(1 << q);
                    ++g;
                }
#pragma unroll
                for (int q = 0; q < 8; ++q) {
                    int cu = rc8 + q;
                    *(u64*)&stage[t & 1][rrow * 512 + ((cu >> 1) ^ (rrow & 7)) * 8 + (cu & 1) * 4] =
                        vv[q] & VMASK;
                }
            }
            __syncthreads();   // stage[t&1] complete for step t+1
        }
    } else {
        // ---------------- layer 1 ----------------
        half8 Bih[2][16], Bhh[2][16];
#pragma unroll
        for (int j = 0; j < 2; ++j) {
#pragma unroll
            for (int kc = 0; kc < 16; ++kc) {
                Bih[j][kc] = *(const half8*)(Wih1 + (size_t)(c0w + j * 16 + lr) * H_DIM
                                             + kc * 32 + quad * 8);
                Bhh[j][kc] = *(const half8*)(Whh1 + (size_t)(c0w + j * 16 + lr) * H_DIM
                                             + kc * 32 + quad * 8);
            }
        }
        const float b1[2] = {bias1[c0w + lr], bias1[c0w + 16 + lr]};

        for (int t = 0; t < T_LEN; ++t) {
            // joint spin: h0_t (all 8 u64/thread) + h1_{t-1} sibs (8, skip own)
            const u64 emA = tagmask(t), emB = tagmask(t - 1);
            u64 va[8], vb[8];
            int pendA = 0xff;
            int pendB = (t > 0 && !mine) ? 0xff : 0;
            u64* srcA = hex0 + ((size_t)(t & 3) * 64 + rows0 + rrow) * 128 + rc8;
            u64* srcB = hex1 + ((size_t)((t - 1) & 3) * 64 + rows0 + rrow) * 128 + rc8;
            int g = 0;
            while ((pendA | pendB) && g < SPIN_LIM) {
#pragma unroll
                for (int q = 0; q < 8; ++q)
                    if (pendA & (1 << q))
                        va[q] = __hip_atomic_fetch_or(srcA + q, 0ull, __ATOMIC_RELAXED,
                                                      __HIP_MEMORY_SCOPE_AGENT);
#pragma unroll
                for (int q = 0; q < 8; ++q)
                    if (pendB & (1 << q))
                        vb[q] = __hip_atomic_fetch_or(srcB + q, 0ull, __ATOMIC_RELAXED,
                                                      __HIP_MEMORY_SCOPE_AGENT);
#pragma unroll
                for (int q = 0; q < 8; ++q) {
                    if ((pendA & (1 << q)) && ((va[q] & SGN) == emA)) pendA &= ~(1 << q);
                    if ((pendB & (1 << q)) && ((vb[q] & SGN) == emB)) pendB &= ~(1 << q);
                }
                ++g;
            }
            // stores into stages
#pragma unroll
            for (int q = 0; q < 8; ++q) {
                int cu = rc8 + q;
                *(u64*)&stage[2 + (t & 1)][rrow * 512 + ((cu >> 1) ^ (rrow & 7)) * 8 + (cu & 1) * 4] =
                    va[q] & VMASK;
            }
            if (t > 0 && !mine) {
#pragma unroll
                for (int q = 0; q < 8; ++q) {
                    int cu = rc8 + q;
                    *(u64*)&stage[(t - 1) & 1][rrow * 512 + ((cu >> 1) ^ (rrow & 7)) * 8 + (cu & 1) * 4] =
                        vb[q] & VMASK;
                }
            }
            __syncthreads();   // stages ready; all h0 reads done
            if (tid == 0)
                (void)__hip_atomic_exchange(&prog[r * 4 + cg], t + 1, __ATOMIC_RELAXED,
                                            __HIP_MEMORY_SCOPE_AGENT);

            float4v acc0 = {0.f,0.f,0.f,0.f}, acc1 = {0.f,0.f,0.f,0.f};
            {
                const f16* sa = stage[2 + (t & 1)];
#pragma unroll
                for (int kc = 0; kc < 16; ++kc) {
                    half8 a = *(const half8*)&sa[lr * 512 + (((kc * 4 + quad) ^ (lr & 7)) * 8)];
                    acc0 = __builtin_amdgcn_mfma_f32_16x16x32_f16(a, Bih[0][kc], acc0, 0, 0, 0);
                    acc1 = __builtin_amdgcn_mfma_f32_16x16x32_f16(a, Bih[1][kc], acc1, 0, 0, 0);
                }
            }
            if (t > 0) {
                const f16* sb = stage[(t - 1) & 1];
#pragma unroll
                for (int kc = 0; kc < 16; ++kc) {
                    half8 a = *(const half8*)&sb[lr * 512 + (((kc * 4 + quad) ^ (lr & 7)) * 8)];
                    acc0 = __builtin_amdgcn_mfma_f32_16x16x32_f16(a, Bhh[0][kc], acc0, 0, 0, 0);
                    acc1 = __builtin_amdgcn_mfma_f32_16x16x32_f16(a, Bhh[1][kc], acc1, 0, 0, 0);
                }
            }

            // h1_t = relu(acc + b1); stage own slice; last step -> hlast
            f16* sw = stage[t & 1];
#pragma unroll
            for (int j = 0; j < 2; ++j) {
                const float4v& a = j ? acc1 : acc0;
#pragma unroll
                for (int i = 0; i < 4; ++i) {
                    float hval = fmaxf(a[i] + b1[j], 0.f);
                    f16 hv = (f16)hval;
                    int row = quad * 4 + i, lc = c0w + j * 16 + lr;
                    sw[row * 512 + ((lc >> 3) ^ (row & 7)) * 8 + (lc & 7)] = hv;
                    if (t == T_LEN - 1)
                        hlast[(size_t)(rows0 + row) * H_DIM + lc] = (float)hv;
                }
            }
            __syncthreads();   // own stage visible to publisher threads

            // publish own 2 u64 (tagged) to hex1
            {
                const u64 em = tagmask(t);
                int cu = cg * 32 + poc;
                uint4 q4 = *(const uint4*)&stage[t & 1][prow * 512 + (((cu >> 1) ^ (prow & 7)) * 8)];
                u64 v0 = (((u64)q4.y) << 32) | q4.x;
                u64 v1 = (((u64)q4.w) << 32) | q4.z;
                u64* dst = hex1 + ((size_t)(t & 3) * 64 + rows0 + prow) * 128;
                (void)__hip_atomic_exchange(&dst[cu], v0 | em, __ATOMIC_RELAXED,
                                            __HIP_MEMORY_SCOPE_AGENT);
                (void)__hip_atomic_exchange(&dst[cu + 1], v1 | em, __ATOMIC_RELAXED,
                                            __HIP_MEMORY_SCOPE_AGENT);
            }
        }
    }
}

// --------------------------- final FC --------------------------------------
__global__ void fc_kernel(const float* __restrict__ hlast, const f16* __restrict__ fcw,
                          const float* __restrict__ fcb, void* __restrict__ out,
                          const int* __restrict__ dtf) {
    int b = blockIdx.x, c = threadIdx.x;
    const float* hrow = hlast + b * H_DIM;
    const f16* wrow = fcw + (size_t)c * H_DIM;
    float s = fcb[c];
    for (int h0 = 0; h0 < H_DIM; h0 += 8) {
        half8 w = *(const half8*)(wrow + h0);
#pragma unroll
        for (int j = 0; j < 8; ++j) s += hrow[h0 + j] * (float)w[j];
    }
    if (*dtf) ((float*)out)[b * 128 + c] = s;
    else      ((u16*)out)[b * 128 + c] = f2bf(s);
}

// --------------------------- launch ----------------------------------------
extern "C" void kernel_launch(void* const* d_in, const int* in_sizes, int n_in,
                              void* d_out, int out_size, void* d_ws, size_t ws_size,
                              hipStream_t stream)
{
    const void* x     = d_in[0];
    const void* W_ih0 = d_in[1];
    const void* W_hh0 = d_in[2];
    const void* b_ih0 = d_in[3];
    const void* b_hh0 = d_in[4];
    const void* W_ih1 = d_in[5];
    const void* W_hh1 = d_in[6];
    const void* b_ih1 = d_in[7];
    const void* b_hh1 = d_in[8];
    const void* fc_w  = d_in[9];
    const void* fc_b  = d_in[10];

    char* ws = (char*)d_ws;
    int*   dtf   = (int*)(ws + 0);            //     64 B
    int*   prog  = (int*)(ws + 64);           //     64 B (16 ints)
    float* bias0 = (float*)(ws + 4096);       //   2048 B
    float* bias1 = (float*)(ws + 6144);       //   2048 B
    float* fcbf  = (float*)(ws + 8192);       //    512 B
    float* hlast = (float*)(ws + 16384);      // 131072 B [64,512] fp32
    u64*   hex0  = (u64*)(ws + 147456);       // 262144 B [4][64][128] u64
    u64*   hex1  = (u64*)(ws + 409600);       // 262144 B
    f16*   Wih0f = (f16*)(ws + 671744);       // 262144 B [512,256]
    f16*   Whh0f = (f16*)(ws + 933888);       // 524288 B [512,512]
    f16*   Wih1f = (f16*)(ws + 1458176);      // 524288 B
    f16*   Whh1f = (f16*)(ws + 1982464);      // 524288 B
    f16*   fcwf  = (f16*)(ws + 2506752);      // 131072 B [128,512]
    // total ~2.6 MB

    detect_kernel<<<dim3(1), dim3(64), 0, stream>>>((const u16*)x, dtf);
    cvt_w_kernel<<<dim3(512), dim3(256), 0, stream>>>(W_ih0, Wih0f, H_DIM * 256, dtf);
    cvt_w_kernel<<<dim3(1024), dim3(256), 0, stream>>>(W_hh0, Whh0f, H_DIM * H_DIM, dtf);
    cvt_w_kernel<<<dim3(1024), dim3(256), 0, stream>>>(W_ih1, Wih1f, H_DIM * H_DIM, dtf);
    cvt_w_kernel<<<dim3(1024), dim3(256), 0, stream>>>(W_hh1, Whh1f, H_DIM * H_DIM, dtf);
    cvt_w_kernel<<<dim3(256), dim3(256), 0, stream>>>(fc_w, fcwf, 128 * H_DIM, dtf);
    bias_kernel<<<dim3(2), dim3(256), 0, stream>>>(b_ih0, b_hh0, bias0, dtf);
    bias_kernel<<<dim3(2), dim3(256), 0, stream>>>(b_ih1, b_hh1, bias1, dtf);
    fcb_kernel<<<dim3(1), dim3(128), 0, stream>>>(fc_b, fcbf, dtf);

    fused_rnn_kernel<<<dim3(32), dim3(256), 0, stream>>>(
        x, Wih0f, Whh0f, Wih1f, Whh1f, bias0, bias1, hex0, hex1, prog, hlast, dtf);

    fc_kernel<<<dim3(B_SZ), dim3(128), 0, stream>>>(hlast, fcwf, fcbf, d_out, dtf);
}